// Round 8
// baseline (1023.674 us; speedup 1.0000x reference)
//
#include <hip/hip_runtime.h>
#include <hip/hip_bf16.h>

typedef __attribute__((ext_vector_type(8))) short short8;
typedef __attribute__((ext_vector_type(4))) float f32x4;

#define NN    2048
#define DDIM  512
#define HDIM  512
#define PP    51
#define NBASE 30
#define PD    26112   // PP*DDIM
#define NKC   17      // split-K factor in G2

static __device__ __forceinline__ short f2bf(float f) {
  __hip_bfloat16 h = __float2bfloat16(f);
  short s;
  __builtin_memcpy(&s, &h, 2);
  return s;
}

#define GLOAD16(gsrc, ldst)                                                              \
  __builtin_amdgcn_global_load_lds((const __attribute__((address_space(1))) void*)(gsrc),\
                                   (__attribute__((address_space(3))) void*)(ldst),      \
                                   16, 0, 0)

// ---------------------------------------------------------------------------
// K0: vertex [2048,512] f32 -> vT [512,2048] bf16
// ---------------------------------------------------------------------------
__global__ __launch_bounds__(256) void k_transpose(const float* __restrict__ vx,
                                                   short* __restrict__ vT) {
  __shared__ float tile[64][68];
  const int t  = threadIdx.x;
  const int mt = blockIdx.x & 31, dt = blockIdx.x >> 5;
  const int m0 = mt * 64, d0 = dt * 64;

  const int r  = t >> 2;
  const int c0 = (t & 3) * 16;
  const float* src = vx + (size_t)(m0 + r) * DDIM + d0 + c0;
#pragma unroll
  for (int j = 0; j < 4; ++j) {
    f32x4 v = *(const f32x4*)(src + j * 4);
    tile[r][c0 + j * 4 + 0] = v[0];
    tile[r][c0 + j * 4 + 1] = v[1];
    tile[r][c0 + j * 4 + 2] = v[2];
    tile[r][c0 + j * 4 + 3] = v[3];
  }
  __syncthreads();
  const int c  = t >> 2;
  const int r0 = (t & 3) * 16;
  short8 o0, o1;
#pragma unroll
  for (int j = 0; j < 8; ++j) {
    o0[j] = f2bf(tile[r0 + j][c]);
    o1[j] = f2bf(tile[r0 + 8 + j][c]);
  }
  short* dst = vT + (size_t)(d0 + c) * NN + m0 + r0;
  *(short8*)(dst)     = o0;
  *(short8*)(dst + 8) = o1;
}

// ---------------------------------------------------------------------------
// K1: BmT [512][26112] bf16 ; BmT[h][d'*51+p] = sum_b Wc[p,b]*W[(b*512+d')*512+h]
// ---------------------------------------------------------------------------
__global__ __launch_bounds__(512) void k_bmt(const float* __restrict__ W,
                                             const float* __restrict__ Wc,
                                             short* __restrict__ BmT) {
  __shared__ float wcs[PP * NBASE];
  __shared__ short Lt[HDIM * PP];
  const int t  = threadIdx.x;
  const int dp = blockIdx.x;

  for (int i = t; i < PP * NBASE; i += 512) wcs[i] = Wc[i];

  float wv[NBASE];
#pragma unroll
  for (int b = 0; b < NBASE; ++b)
    wv[b] = W[((size_t)(b * DDIM + dp)) * HDIM + t];
  __syncthreads();

#pragma unroll 1
  for (int p = 0; p < PP; ++p) {
    float acc = 0.f;
#pragma unroll
    for (int b = 0; b < NBASE; ++b) acc += wcs[p * NBASE + b] * wv[b];
    Lt[t * PP + p] = f2bf(acc);
  }
  __syncthreads();

  for (int idx = t; idx < HDIM * PP; idx += 512) {
    const int h = idx / PP;
    const int p = idx - h * PP;
    BmT[(size_t)h * PD + dp * PP + p] = Lt[idx];
  }
}

// ---------------------------------------------------------------------------
// G1: SF[n][p*512+d] = sum_m A[p,n,m]*vertex[m,d]
// grid 816 = 51p x 16n ; 1024 thr (16 waves 2x8) ; tile 128(n) x 512(d) x BK64
// 2-DEEP A prefetch: tail(kt) issues B(kt+2) then A(kt+3)->R[(kt+1)&1];
// stage(kt) consumes A(kt+1) issued TWO iters earlier. Steady-state queue
// before iter-kt wait: [A(kt+1)x2, B(kt+1)x4, A(kt+2)x2] -> vmcnt(2) retires
// the 6 oldest (all landed), keeps A(kt+2). Queue never drains below 2.
// ---------------------------------------------------------------------------
__global__ __launch_bounds__(1024, 4) void g_supports(const float* __restrict__ A,
                                                      const short* __restrict__ vT,
                                                      short* __restrict__ SF) {
  __shared__ __align__(16) char Asb[128 * 64 * 2];        // 16 KB
  __shared__ __align__(16) char Bsb[2][512 * 64 * 2];     // 2 x 64 KB
  const int t    = threadIdx.x;
  const int p    = blockIdx.x >> 4;
  const int n0   = (blockIdx.x & 15) << 7;
  const int lane = t & 63, w = t >> 6;        // 16 waves
  const int wr = w >> 3, wc = w & 7;          // 2 x 8 wave grid
  const int l15 = lane & 15, q4 = lane >> 4;

  // A staging: thread t stages row t>>3 (128 rows, 8 thr/row), 8 f32 at col (t&7)*8
  const int arow = t >> 3;
  const int ac16 = (t & 7) << 4;
  char* aw = Asb + arow * 128 + (ac16 ^ ((arow & 7) << 4));
  const float* Arow = A + (size_t)p * NN * NN + (size_t)(n0 + arow) * NN + ((t & 7) << 3);

  f32x4 acc[4][4];
#pragma unroll
  for (int i = 0; i < 4; ++i)
#pragma unroll
    for (int j = 0; j < 4; ++j) acc[i][j] = (f32x4){0.f, 0.f, 0.f, 0.f};

  // two A register sets (2-deep prefetch)
  f32x4 a0lo, a0hi;   // set R0
  f32x4 a1lo, a1hi;   // set R1

#define G1_ISSUE_B(buf, kt)                                                        \
  {                                                                                \
    _Pragma("unroll")                                                              \
    for (int i = 0; i < 4; ++i) {                                                  \
      const int L   = t * 16 + i * 16384;                                          \
      const int row = L >> 7;                                                      \
      const int cb  = L & 127;                                                     \
      const char* g = (const char*)vT + (size_t)row * (NN * 2) + (kt) * 128        \
                    + (cb ^ ((row & 7) << 4));                                     \
      GLOAD16(g, Bsb[buf] + L);                                                    \
    }                                                                              \
  }

#define G1_ISSUE_A(kt, rlo, rhi)                                                   \
  {                                                                                \
    const f32x4* s = (const f32x4*)(Arow + (kt) * 64);                             \
    rlo = s[0]; rhi = s[1];                                                        \
  }

#define G1_STAGE_A(rlo, rhi)                                                       \
  {                                                                                \
    short8 s0;                                                                     \
    _Pragma("unroll")                                                              \
    for (int j = 0; j < 4; ++j) {                                                  \
      s0[j]     = f2bf(rlo[j]);                                                    \
      s0[j + 4] = f2bf(rhi[j]);                                                    \
    }                                                                              \
    *(short8*)aw = s0;                                                             \
  }

#define G1_COMPUTE(buf)                                                            \
  {                                                                                \
    _Pragma("unroll")                                                              \
    for (int ks = 0; ks < 2; ++ks) {                                               \
      const int kb = ks * 64 + q4 * 16;                                            \
      short8 af[4], bfr[4];                                                        \
      _Pragma("unroll")                                                            \
      for (int mi = 0; mi < 4; ++mi) {                                             \
        const int row = wr * 64 + mi * 16 + l15;                                   \
        af[mi] = *(const short8*)(Asb + row * 128 + (kb ^ ((row & 7) << 4)));      \
      }                                                                            \
      _Pragma("unroll")                                                            \
      for (int ni = 0; ni < 4; ++ni) {                                             \
        const int row = wc * 64 + ni * 16 + l15;                                   \
        bfr[ni] = *(const short8*)(Bsb[buf] + row * 128 + (kb ^ ((row & 7) << 4)));\
      }                                                                            \
      _Pragma("unroll")                                                            \
      for (int mi = 0; mi < 4; ++mi)                                               \
        _Pragma("unroll")                                                          \
        for (int ni = 0; ni < 4; ++ni)                                             \
          acc[mi][ni] = __builtin_amdgcn_mfma_f32_16x16x32_bf16(af[mi], bfr[ni],   \
                                                                acc[mi][ni], 0, 0, 0);\
    }                                                                              \
  }

// one pipeline iteration; RS = reg set holding A(kt+1), refilled with A(kt+3)
#define G1_ITER(kt, rlo, rhi)                                                      \
  {                                                                                \
    __builtin_amdgcn_s_setprio(1);                                                 \
    G1_COMPUTE((kt) & 1);                                                          \
    __builtin_amdgcn_s_setprio(0);                                                 \
    asm volatile("s_waitcnt vmcnt(2)" ::: "memory");                               \
    __builtin_amdgcn_sched_barrier(0);                                             \
    __builtin_amdgcn_s_barrier();        /* done reading Asb/Bsb[kt&1]; A+B landed */\
    G1_STAGE_A(rlo, rhi);                /* stage A(kt+1), issued 2 iters ago */    \
    {                                                                              \
      const int nk2 = ((kt) + 2 < 32) ? (kt) + 2 : 31;                             \
      const int nk3 = ((kt) + 3 < 32) ? (kt) + 3 : 31;                             \
      G1_ISSUE_B((kt) & 1, nk2);         /* into buffer just freed */              \
      G1_ISSUE_A(nk3, rlo, rhi);         /* refill same set, 2-deep */             \
    }                                                                              \
    asm volatile("s_waitcnt lgkmcnt(0)" ::: "memory");                             \
    __builtin_amdgcn_sched_barrier(0);                                             \
    __builtin_amdgcn_s_barrier();        /* Asb(kt+1) visible */                   \
  }

  // ---- prologue: Asb=A(0); queue = [A(1)x2, B(1)x4, A(2)x2] oldest-first ----
  G1_ISSUE_A(0, a0lo, a0hi);
  G1_ISSUE_B(0, 0);
  G1_STAGE_A(a0lo, a0hi);        // waits A(0) (full drain; prologue only)
  G1_ISSUE_A(1, a1lo, a1hi);     // -> R1, consumed at stage(0)
  G1_ISSUE_B(1, 1);
  G1_ISSUE_A(2, a0lo, a0hi);     // -> R0, consumed at stage(1)
  asm volatile("s_waitcnt lgkmcnt(0)" ::: "memory");
  __builtin_amdgcn_sched_barrier(0);
  __builtin_amdgcn_s_barrier();

  // even kt consumes R1, odd kt consumes R0
#pragma unroll 1
  for (int kt = 0; kt < 32; kt += 2) {
    G1_ITER(kt,     a1lo, a1hi);
    G1_ITER(kt + 1, a0lo, a0hi);
  }

  // ---- epilogue: C row = 4*q4+qq, col = l15 ----
#pragma unroll
  for (int mi = 0; mi < 4; ++mi) {
    const int nr = n0 + wr * 64 + mi * 16 + q4 * 4;
#pragma unroll
    for (int ni = 0; ni < 4; ++ni) {
      const int dc = p * DDIM + wc * 64 + ni * 16 + l15;
#pragma unroll
      for (int qq = 0; qq < 4; ++qq)
        SF[(size_t)(nr + qq) * PD + dc] = f2bf(acc[mi][ni][qq]);
    }
  }
#undef G1_ISSUE_B
#undef G1_ISSUE_A
#undef G1_STAGE_A
#undef G1_COMPUTE
#undef G1_ITER
}

// ---------------------------------------------------------------------------
// G2: part[kc][n][h] = sum_{r in chunk kc} SF[n,r]*BmT[h,r]   (r6 proven)
// grid 544 = 17kc x 16n x 2h ; tile 128 x 256 x BK64 ; 48 KB LDS, 3 blk/CU
// ---------------------------------------------------------------------------
__global__ __launch_bounds__(512) void g_out_part(const short* __restrict__ SF,
                                                  const short* __restrict__ BmT,
                                                  float* __restrict__ part) {
  __shared__ __align__(16) char Asb[128 * 64 * 2];
  __shared__ __align__(16) char Bsb[256 * 64 * 2];
  const int t   = threadIdx.x;
  const int bid = blockIdx.x;
  const int kc  = bid >> 5;
  const int rem = bid & 31;
  const int n0  = (rem >> 1) * 128;
  const int h0  = (rem & 1) * 256;
  const int rbase = kc * 1536;
  const int lane = t & 63, w = t >> 6;
  const int wr = w >> 2, wc = w & 3;
  const int l15 = lane & 15, q4 = lane >> 4;

  f32x4 acc[4][4];
#pragma unroll
  for (int i = 0; i < 4; ++i)
#pragma unroll
    for (int j = 0; j < 4; ++j) acc[i][j] = (f32x4){0.f, 0.f, 0.f, 0.f};

  for (int kt = 0; kt < 24; ++kt) {
    const int rk = rbase + (kt << 6);
    __syncthreads();
#pragma unroll
    for (int i = 0; i < 2; ++i) {
      const int L   = t * 16 + i * 8192;
      const int row = L >> 7, cb = L & 127;
      const char* g = (const char*)SF + ((size_t)(n0 + row) * PD + rk) * 2
                    + (cb ^ ((row & 7) << 4));
      GLOAD16(g, Asb + L);
    }
#pragma unroll
    for (int i = 0; i < 4; ++i) {
      const int L   = t * 16 + i * 8192;
      const int row = L >> 7, cb = L & 127;
      const char* g = (const char*)BmT + ((size_t)(h0 + row) * PD + rk) * 2
                    + (cb ^ ((row & 7) << 4));
      GLOAD16(g, Bsb + L);
    }
    __syncthreads();
#pragma unroll
    for (int ks = 0; ks < 2; ++ks) {
      const int kb = ks * 64 + q4 * 16;
      short8 af[4], bfr[4];
#pragma unroll
      for (int mi = 0; mi < 4; ++mi) {
        const int row = wr * 64 + mi * 16 + l15;
        af[mi] = *(const short8*)(Asb + row * 128 + (kb ^ ((row & 7) << 4)));
      }
#pragma unroll
      for (int ni = 0; ni < 4; ++ni) {
        const int row = wc * 64 + ni * 16 + l15;
        bfr[ni] = *(const short8*)(Bsb + row * 128 + (kb ^ ((row & 7) << 4)));
      }
#pragma unroll
      for (int mi = 0; mi < 4; ++mi)
#pragma unroll
        for (int ni = 0; ni < 4; ++ni)
          acc[mi][ni] = __builtin_amdgcn_mfma_f32_16x16x32_bf16(af[mi], bfr[ni],
                                                                acc[mi][ni], 0, 0, 0);
    }
  }

  float* dst = part + (size_t)kc * (NN * HDIM);
#pragma unroll
  for (int mi = 0; mi < 4; ++mi) {
    const int nr = n0 + wr * 64 + mi * 16 + q4 * 4;
#pragma unroll
    for (int ni = 0; ni < 4; ++ni) {
      const int hc = h0 + wc * 64 + ni * 16 + l15;
#pragma unroll
      for (int qq = 0; qq < 4; ++qq)
        dst[(size_t)(nr + qq) * HDIM + hc] = acc[mi][ni][qq];
    }
  }
}

// ---------------------------------------------------------------------------
// K3: out[n,h] = B[h] + sum_kc part[kc][n][h]    (f32x4, fully coalesced)
// ---------------------------------------------------------------------------
__global__ __launch_bounds__(256) void k_reduce(const float* __restrict__ part,
                                                const float* __restrict__ B,
                                                float* __restrict__ out) {
  const int flat = (blockIdx.x * 256 + threadIdx.x) * 4;
  f32x4 s = *(const f32x4*)(B + (flat & (HDIM - 1)));
#pragma unroll
  for (int kc = 0; kc < NKC; ++kc)
    s += *(const f32x4*)(part + (size_t)kc * (NN * HDIM) + flat);
  *(f32x4*)(out + flat) = s;
}

// ---------------------------------------------------------------------------
// Workspace map (ws ~3.3 GB):
//   vT   [  0 MiB,   2 MiB)
//   BmT  [  2 MiB,  27.5MiB)
//   SF   [ 32 MiB, 134 MiB)
//   part [144 MiB, 212 MiB)
// ---------------------------------------------------------------------------
extern "C" void kernel_launch(void* const* d_in, const int* in_sizes, int n_in,
                              void* d_out, int out_size, void* d_ws, size_t ws_size,
                              hipStream_t stream) {
  const float* vertex = (const float*)d_in[0];
  const float* A      = (const float*)d_in[1];
  const float* W      = (const float*)d_in[2];
  const float* Wc     = (const float*)d_in[3];
  const float* B      = (const float*)d_in[4];
  float* out = (float*)d_out;

  char* ws   = (char*)d_ws;
  short* vT   = (short*)(ws);
  short* BmT  = (short*)(ws + (size_t)(2   << 20));
  short* SF   = (short*)(ws + (size_t)(32  << 20));
  float* part = (float*)(ws + (size_t)(144 << 20));

  k_transpose<<<dim3(256),  dim3(256),  0, stream>>>(vertex, vT);
  k_bmt      <<<dim3(512),  dim3(512),  0, stream>>>(W, Wc, BmT);
  g_supports <<<dim3(816),  dim3(1024), 0, stream>>>(A, vT, SF);
  g_out_part <<<dim3(544),  dim3(512),  0, stream>>>(SF, BmT, part);
  k_reduce   <<<dim3(1024), dim3(256),  0, stream>>>(part, B, out);
}

// Round 9
// 711.271 us; speedup vs baseline: 1.4392x; 1.4392x over previous
//
#include <hip/hip_runtime.h>
#include <hip/hip_bf16.h>

typedef __attribute__((ext_vector_type(8))) short short8;
typedef __attribute__((ext_vector_type(4))) float f32x4;

#define NN    2048
#define DDIM  512
#define HDIM  512
#define PP    51
#define NBASE 30
#define PD    26112   // PP*DDIM
#define NKC   17      // split-K factor in G2

static __device__ __forceinline__ short f2bf(float f) {
  __hip_bfloat16 h = __float2bfloat16(f);
  short s;
  __builtin_memcpy(&s, &h, 2);
  return s;
}

#define GLOAD16(gsrc, ldst)                                                              \
  __builtin_amdgcn_global_load_lds((const __attribute__((address_space(1))) void*)(gsrc),\
                                   (__attribute__((address_space(3))) void*)(ldst),      \
                                   16, 0, 0)

// ---------------------------------------------------------------------------
// K0: vertex [2048,512] f32 -> vT [512,2048] bf16
// ---------------------------------------------------------------------------
__global__ __launch_bounds__(256) void k_transpose(const float* __restrict__ vx,
                                                   short* __restrict__ vT) {
  __shared__ float tile[64][68];
  const int t  = threadIdx.x;
  const int mt = blockIdx.x & 31, dt = blockIdx.x >> 5;
  const int m0 = mt * 64, d0 = dt * 64;

  const int r  = t >> 2;
  const int c0 = (t & 3) * 16;
  const float* src = vx + (size_t)(m0 + r) * DDIM + d0 + c0;
#pragma unroll
  for (int j = 0; j < 4; ++j) {
    f32x4 v = *(const f32x4*)(src + j * 4);
    tile[r][c0 + j * 4 + 0] = v[0];
    tile[r][c0 + j * 4 + 1] = v[1];
    tile[r][c0 + j * 4 + 2] = v[2];
    tile[r][c0 + j * 4 + 3] = v[3];
  }
  __syncthreads();
  const int c  = t >> 2;
  const int r0 = (t & 3) * 16;
  short8 o0, o1;
#pragma unroll
  for (int j = 0; j < 8; ++j) {
    o0[j] = f2bf(tile[r0 + j][c]);
    o1[j] = f2bf(tile[r0 + 8 + j][c]);
  }
  short* dst = vT + (size_t)(d0 + c) * NN + m0 + r0;
  *(short8*)(dst)     = o0;
  *(short8*)(dst + 8) = o1;
}

// ---------------------------------------------------------------------------
// K1: BmT [512][26112] bf16 ; BmT[h][d'*51+p] = sum_b Wc[p,b]*W[(b*512+d')*512+h]
// ---------------------------------------------------------------------------
__global__ __launch_bounds__(512) void k_bmt(const float* __restrict__ W,
                                             const float* __restrict__ Wc,
                                             short* __restrict__ BmT) {
  __shared__ float wcs[PP * NBASE];
  __shared__ short Lt[HDIM * PP];
  const int t  = threadIdx.x;
  const int dp = blockIdx.x;

  for (int i = t; i < PP * NBASE; i += 512) wcs[i] = Wc[i];

  float wv[NBASE];
#pragma unroll
  for (int b = 0; b < NBASE; ++b)
    wv[b] = W[((size_t)(b * DDIM + dp)) * HDIM + t];
  __syncthreads();

#pragma unroll 1
  for (int p = 0; p < PP; ++p) {
    float acc = 0.f;
#pragma unroll
    for (int b = 0; b < NBASE; ++b) acc += wcs[p * NBASE + b] * wv[b];
    Lt[t * PP + p] = f2bf(acc);
  }
  __syncthreads();

  for (int idx = t; idx < HDIM * PP; idx += 512) {
    const int h = idx / PP;
    const int p = idx - h * PP;
    BmT[(size_t)h * PD + dp * PP + p] = Lt[idx];
  }
}

// ---------------------------------------------------------------------------
// G1: SF[n][p*512+d] = sum_m A[p,n,m]*vertex[m,d]
// grid 272 = 17 p-triples x 16 n ; 1024 thr (16 waves 2x8) ;
// per p: tile 128(n) x 512(d) x BK64, r3/r6-proven schedule.
// p-TRIPLE: each block runs 3 sequential K-loops (p0,p0+1,p0+2) so passes
// 2-3 re-read vT from warm L2 -> vT HBM traffic 1.63 GB -> 544 MB.
// Between passes: vmcnt(0)+barrier (drains stray Bsb prefetches, protects Asb).
// ---------------------------------------------------------------------------
__global__ __launch_bounds__(1024, 4) void g_supports(const float* __restrict__ A,
                                                      const short* __restrict__ vT,
                                                      short* __restrict__ SF) {
  __shared__ __align__(16) char Asb[128 * 64 * 2];        // 16 KB
  __shared__ __align__(16) char Bsb[2][512 * 64 * 2];     // 2 x 64 KB
  const int t    = threadIdx.x;
  const int ptri = blockIdx.x >> 4;           // 0..16
  const int n0   = (blockIdx.x & 15) << 7;
  const int lane = t & 63, w = t >> 6;        // 16 waves
  const int wr = w >> 3, wc = w & 7;          // 2 x 8 wave grid
  const int l15 = lane & 15, q4 = lane >> 4;

  // A staging: thread t stages row t>>3 (128 rows, 8 thr/row), 8 f32 at col (t&7)*8
  const int arow = t >> 3;
  const int ac16 = (t & 7) << 4;
  char* aw = Asb + arow * 128 + (ac16 ^ ((arow & 7) << 4));
  const float* Abase = A + (size_t)(ptri * 3) * NN * NN
                         + (size_t)(n0 + arow) * NN + ((t & 7) << 3);

  f32x4 acc[4][4];
  f32x4 ar0, ar1;

#define G1_ISSUE_B(buf, kt)                                                        \
  {                                                                                \
    _Pragma("unroll")                                                              \
    for (int i = 0; i < 4; ++i) {                                                  \
      const int L   = t * 16 + i * 16384;                                          \
      const int row = L >> 7;                                                      \
      const int cb  = L & 127;                                                     \
      const char* g = (const char*)vT + (size_t)row * (NN * 2) + (kt) * 128        \
                    + (cb ^ ((row & 7) << 4));                                     \
      GLOAD16(g, Bsb[buf] + L);                                                    \
    }                                                                              \
  }

#define G1_ISSUE_A(kt)                                                             \
  {                                                                                \
    const f32x4* s = (const f32x4*)(Arow + (kt) * 64);                             \
    ar0 = s[0]; ar1 = s[1];                                                        \
  }

#define G1_STAGE_A()                                                               \
  {                                                                                \
    short8 s0;                                                                     \
    _Pragma("unroll")                                                              \
    for (int j = 0; j < 4; ++j) {                                                  \
      s0[j]     = f2bf(ar0[j]);                                                    \
      s0[j + 4] = f2bf(ar1[j]);                                                    \
    }                                                                              \
    *(short8*)aw = s0;                                                             \
  }

#define G1_COMPUTE(buf)                                                            \
  {                                                                                \
    _Pragma("unroll")                                                              \
    for (int ks = 0; ks < 2; ++ks) {                                               \
      const int kb = ks * 64 + q4 * 16;                                            \
      short8 af[4], bfr[4];                                                        \
      _Pragma("unroll")                                                            \
      for (int mi = 0; mi < 4; ++mi) {                                             \
        const int row = wr * 64 + mi * 16 + l15;                                   \
        af[mi] = *(const short8*)(Asb + row * 128 + (kb ^ ((row & 7) << 4)));      \
      }                                                                            \
      _Pragma("unroll")                                                            \
      for (int ni = 0; ni < 4; ++ni) {                                             \
        const int row = wc * 64 + ni * 16 + l15;                                   \
        bfr[ni] = *(const short8*)(Bsb[buf] + row * 128 + (kb ^ ((row & 7) << 4)));\
      }                                                                            \
      _Pragma("unroll")                                                            \
      for (int mi = 0; mi < 4; ++mi)                                               \
        _Pragma("unroll")                                                          \
        for (int ni = 0; ni < 4; ++ni)                                             \
          acc[mi][ni] = __builtin_amdgcn_mfma_f32_16x16x32_bf16(af[mi], bfr[ni],   \
                                                                acc[mi][ni], 0, 0, 0);\
    }                                                                              \
  }

#pragma unroll 1
  for (int pi = 0; pi < 3; ++pi) {
    const float* Arow = Abase + (size_t)pi * NN * NN;
    const int p = ptri * 3 + pi;

    if (pi) {   // drain stray prefetches; all waves done with LDS of prev pass
      asm volatile("s_waitcnt vmcnt(0)" ::: "memory");
      __builtin_amdgcn_sched_barrier(0);
      __builtin_amdgcn_s_barrier();
    }

#pragma unroll
    for (int i = 0; i < 4; ++i)
#pragma unroll
      for (int j = 0; j < 4; ++j) acc[i][j] = (f32x4){0.f, 0.f, 0.f, 0.f};

    // ---- prologue ----
    G1_ISSUE_A(0);
    G1_ISSUE_B(0, 0);
    G1_STAGE_A();              // compiler waits A(0) -> full drain (per-pass once)
    G1_ISSUE_B(1, 1);
    G1_ISSUE_A(1);
    asm volatile("s_waitcnt lgkmcnt(0)" ::: "memory");
    __builtin_amdgcn_sched_barrier(0);
    __builtin_amdgcn_s_barrier();

#pragma unroll 1
    for (int kt = 0; kt < 31; ++kt) {
      __builtin_amdgcn_s_setprio(1);
      G1_COMPUTE(kt & 1);
      __builtin_amdgcn_s_setprio(0);

      asm volatile("s_waitcnt vmcnt(2)" ::: "memory");
      __builtin_amdgcn_sched_barrier(0);
      __builtin_amdgcn_s_barrier();

      G1_STAGE_A();
      if (kt + 2 < 32) {
        G1_ISSUE_B(kt & 1, kt + 2);
        G1_ISSUE_A(kt + 2);
      }
      asm volatile("s_waitcnt lgkmcnt(0)" ::: "memory");
      __builtin_amdgcn_sched_barrier(0);
      __builtin_amdgcn_s_barrier();
    }
    G1_COMPUTE(1);             // tile 31

    // ---- epilogue: C row = 4*q4+qq, col = l15 ----
#pragma unroll
    for (int mi = 0; mi < 4; ++mi) {
      const int nr = n0 + wr * 64 + mi * 16 + q4 * 4;
#pragma unroll
      for (int ni = 0; ni < 4; ++ni) {
        const int dc = p * DDIM + wc * 64 + ni * 16 + l15;
#pragma unroll
        for (int qq = 0; qq < 4; ++qq)
          SF[(size_t)(nr + qq) * PD + dc] = f2bf(acc[mi][ni][qq]);
      }
    }
  }
#undef G1_ISSUE_B
#undef G1_ISSUE_A
#undef G1_STAGE_A
#undef G1_COMPUTE
}

// ---------------------------------------------------------------------------
// G2: part[kc][n][h] = sum_{r in chunk kc} SF[n,r]*BmT[h,r]   (r6 proven)
// grid 544 = 17kc x 16n x 2h ; tile 128 x 256 x BK64 ; 48 KB LDS, 3 blk/CU
// ---------------------------------------------------------------------------
__global__ __launch_bounds__(512) void g_out_part(const short* __restrict__ SF,
                                                  const short* __restrict__ BmT,
                                                  float* __restrict__ part) {
  __shared__ __align__(16) char Asb[128 * 64 * 2];
  __shared__ __align__(16) char Bsb[256 * 64 * 2];
  const int t   = threadIdx.x;
  const int bid = blockIdx.x;
  const int kc  = bid >> 5;
  const int rem = bid & 31;
  const int n0  = (rem >> 1) * 128;
  const int h0  = (rem & 1) * 256;
  const int rbase = kc * 1536;
  const int lane = t & 63, w = t >> 6;
  const int wr = w >> 2, wc = w & 3;
  const int l15 = lane & 15, q4 = lane >> 4;

  f32x4 acc[4][4];
#pragma unroll
  for (int i = 0; i < 4; ++i)
#pragma unroll
    for (int j = 0; j < 4; ++j) acc[i][j] = (f32x4){0.f, 0.f, 0.f, 0.f};

  for (int kt = 0; kt < 24; ++kt) {
    const int rk = rbase + (kt << 6);
    __syncthreads();
#pragma unroll
    for (int i = 0; i < 2; ++i) {
      const int L   = t * 16 + i * 8192;
      const int row = L >> 7, cb = L & 127;
      const char* g = (const char*)SF + ((size_t)(n0 + row) * PD + rk) * 2
                    + (cb ^ ((row & 7) << 4));
      GLOAD16(g, Asb + L);
    }
#pragma unroll
    for (int i = 0; i < 4; ++i) {
      const int L   = t * 16 + i * 8192;
      const int row = L >> 7, cb = L & 127;
      const char* g = (const char*)BmT + ((size_t)(h0 + row) * PD + rk) * 2
                    + (cb ^ ((row & 7) << 4));
      GLOAD16(g, Bsb + L);
    }
    __syncthreads();
#pragma unroll
    for (int ks = 0; ks < 2; ++ks) {
      const int kb = ks * 64 + q4 * 16;
      short8 af[4], bfr[4];
#pragma unroll
      for (int mi = 0; mi < 4; ++mi) {
        const int row = wr * 64 + mi * 16 + l15;
        af[mi] = *(const short8*)(Asb + row * 128 + (kb ^ ((row & 7) << 4)));
      }
#pragma unroll
      for (int ni = 0; ni < 4; ++ni) {
        const int row = wc * 64 + ni * 16 + l15;
        bfr[ni] = *(const short8*)(Bsb + row * 128 + (kb ^ ((row & 7) << 4)));
      }
#pragma unroll
      for (int mi = 0; mi < 4; ++mi)
#pragma unroll
        for (int ni = 0; ni < 4; ++ni)
          acc[mi][ni] = __builtin_amdgcn_mfma_f32_16x16x32_bf16(af[mi], bfr[ni],
                                                                acc[mi][ni], 0, 0, 0);
    }
  }

  float* dst = part + (size_t)kc * (NN * HDIM);
#pragma unroll
  for (int mi = 0; mi < 4; ++mi) {
    const int nr = n0 + wr * 64 + mi * 16 + q4 * 4;
#pragma unroll
    for (int ni = 0; ni < 4; ++ni) {
      const int hc = h0 + wc * 64 + ni * 16 + l15;
#pragma unroll
      for (int qq = 0; qq < 4; ++qq)
        dst[(size_t)(nr + qq) * HDIM + hc] = acc[mi][ni][qq];
    }
  }
}

// ---------------------------------------------------------------------------
// K3: out[n,h] = B[h] + sum_kc part[kc][n][h]    (f32x4, fully coalesced)
// ---------------------------------------------------------------------------
__global__ __launch_bounds__(256) void k_reduce(const float* __restrict__ part,
                                                const float* __restrict__ B,
                                                float* __restrict__ out) {
  const int flat = (blockIdx.x * 256 + threadIdx.x) * 4;
  f32x4 s = *(const f32x4*)(B + (flat & (HDIM - 1)));
#pragma unroll
  for (int kc = 0; kc < NKC; ++kc)
    s += *(const f32x4*)(part + (size_t)kc * (NN * HDIM) + flat);
  *(f32x4*)(out + flat) = s;
}

// ---------------------------------------------------------------------------
// Workspace map (ws ~3.3 GB):
//   vT   [  0 MiB,   2 MiB)
//   BmT  [  2 MiB,  27.5MiB)
//   SF   [ 32 MiB, 134 MiB)
//   part [144 MiB, 212 MiB)
// ---------------------------------------------------------------------------
extern "C" void kernel_launch(void* const* d_in, const int* in_sizes, int n_in,
                              void* d_out, int out_size, void* d_ws, size_t ws_size,
                              hipStream_t stream) {
  const float* vertex = (const float*)d_in[0];
  const float* A      = (const float*)d_in[1];
  const float* W      = (const float*)d_in[2];
  const float* Wc     = (const float*)d_in[3];
  const float* B      = (const float*)d_in[4];
  float* out = (float*)d_out;

  char* ws   = (char*)d_ws;
  short* vT   = (short*)(ws);
  short* BmT  = (short*)(ws + (size_t)(2   << 20));
  short* SF   = (short*)(ws + (size_t)(32  << 20));
  float* part = (float*)(ws + (size_t)(144 << 20));

  k_transpose<<<dim3(256),  dim3(256),  0, stream>>>(vertex, vT);
  k_bmt      <<<dim3(512),  dim3(512),  0, stream>>>(W, Wc, BmT);
  g_supports <<<dim3(272),  dim3(1024), 0, stream>>>(A, vT, SF);
  g_out_part <<<dim3(544),  dim3(512),  0, stream>>>(SF, BmT, part);
  k_reduce   <<<dim3(1024), dim3(256),  0, stream>>>(part, B, out);
}

// Round 10
// 534.644 us; speedup vs baseline: 1.9147x; 1.3304x over previous
//
#include <hip/hip_runtime.h>
#include <hip/hip_bf16.h>

typedef __attribute__((ext_vector_type(8))) short short8;
typedef __attribute__((ext_vector_type(4))) float f32x4;

#define NN    2048
#define DDIM  512
#define HDIM  512
#define PP    51
#define NBASE 30
#define PD    26112   // PP*DDIM
#define NKC   17      // split-K factor in G2

static __device__ __forceinline__ short f2bf(float f) {
  __hip_bfloat16 h = __float2bfloat16(f);
  short s;
  __builtin_memcpy(&s, &h, 2);
  return s;
}

#define GLOAD16(gsrc, ldst)                                                              \
  __builtin_amdgcn_global_load_lds((const __attribute__((address_space(1))) void*)(gsrc),\
                                   (__attribute__((address_space(3))) void*)(ldst),      \
                                   16, 0, 0)

// ---------------------------------------------------------------------------
// K0: vertex [2048,512] f32 -> vT [512,2048] bf16
// ---------------------------------------------------------------------------
__global__ __launch_bounds__(256) void k_transpose(const float* __restrict__ vx,
                                                   short* __restrict__ vT) {
  __shared__ float tile[64][68];
  const int t  = threadIdx.x;
  const int mt = blockIdx.x & 31, dt = blockIdx.x >> 5;
  const int m0 = mt * 64, d0 = dt * 64;

  const int r  = t >> 2;
  const int c0 = (t & 3) * 16;
  const float* src = vx + (size_t)(m0 + r) * DDIM + d0 + c0;
#pragma unroll
  for (int j = 0; j < 4; ++j) {
    f32x4 v = *(const f32x4*)(src + j * 4);
    tile[r][c0 + j * 4 + 0] = v[0];
    tile[r][c0 + j * 4 + 1] = v[1];
    tile[r][c0 + j * 4 + 2] = v[2];
    tile[r][c0 + j * 4 + 3] = v[3];
  }
  __syncthreads();
  const int c  = t >> 2;
  const int r0 = (t & 3) * 16;
  short8 o0, o1;
#pragma unroll
  for (int j = 0; j < 8; ++j) {
    o0[j] = f2bf(tile[r0 + j][c]);
    o1[j] = f2bf(tile[r0 + 8 + j][c]);
  }
  short* dst = vT + (size_t)(d0 + c) * NN + m0 + r0;
  *(short8*)(dst)     = o0;
  *(short8*)(dst + 8) = o1;
}

// ---------------------------------------------------------------------------
// K1: BmT [512][26112] bf16 ; BmT[h][d'*51+p] = sum_b Wc[p,b]*W[(b*512+d')*512+h]
// ---------------------------------------------------------------------------
__global__ __launch_bounds__(512) void k_bmt(const float* __restrict__ W,
                                             const float* __restrict__ Wc,
                                             short* __restrict__ BmT) {
  __shared__ float wcs[PP * NBASE];
  __shared__ short Lt[HDIM * PP];
  const int t  = threadIdx.x;
  const int dp = blockIdx.x;

  for (int i = t; i < PP * NBASE; i += 512) wcs[i] = Wc[i];

  float wv[NBASE];
#pragma unroll
  for (int b = 0; b < NBASE; ++b)
    wv[b] = W[((size_t)(b * DDIM + dp)) * HDIM + t];
  __syncthreads();

#pragma unroll 1
  for (int p = 0; p < PP; ++p) {
    float acc = 0.f;
#pragma unroll
    for (int b = 0; b < NBASE; ++b) acc += wcs[p * NBASE + b] * wv[b];
    Lt[t * PP + p] = f2bf(acc);
  }
  __syncthreads();

  for (int idx = t; idx < HDIM * PP; idx += 512) {
    const int h = idx / PP;
    const int p = idx - h * PP;
    BmT[(size_t)h * PD + dp * PP + p] = Lt[idx];
  }
}

// ---------------------------------------------------------------------------
// G1: SF[n][p*512+d] = sum_m A[p,n,m]*vertex[m,d]
// grid 816 = 51p x 16n ; 1024 thr (16 waves 2x8) ; tile 128(n) x 512(d) x BK32
// BOTH operands via global_load_lds, TRIPLE-buffered (48 KB/tile x3 = 144 KB):
//   A tile f32 128x32 (16 KB, 128-B rows, XOR (row&7)<<4), cvt at frag-load
//   B tile bf16 512x32 (32 KB, 64-B rows, slot-XOR q4^(row&3))
// Per iter: vmcnt(3) + ONE barrier + issue tile(kt+2) + 16 MFMA/wave.
// Prefetch distance = 2 iters. No register staging, no mid-iter drains.
// ---------------------------------------------------------------------------
__global__ __launch_bounds__(1024, 4) void g_supports(const float* __restrict__ A,
                                                      const short* __restrict__ vT,
                                                      short* __restrict__ SF) {
  __shared__ __align__(16) char lds[147456];   // A: 0,16K,32K ; B: 48K,80K,112K
  const int t    = threadIdx.x;
  const int p    = blockIdx.x >> 4;
  const int n0   = (blockIdx.x & 15) << 7;
  const int lane = t & 63, w = t >> 6;        // 16 waves
  const int wr = w >> 3, wc = w & 7;          // 2 x 8 wave grid, wave tile 64x64
  const int l15 = lane & 15, q4 = lane >> 4;

  // A-issue geometry: L = t*16 covers 16 KB; row = L>>7, cb = L&127
  const int  a_row = t >> 3;
  const int  a_cb  = (t & 7) << 4;
  const char* Agbase = (const char*)A
      + ((size_t)p * NN * NN + (size_t)(n0 + a_row) * NN) * 4
      + (a_cb ^ ((a_row & 7) << 4));
  const int a_ldst = t * 16;

  // B-issue geometry: L = t*16 + i*16384 ; row = L>>6, slot = (L>>4)&3
  const int  b_row0 = t >> 2;            // i=0 rows 0..255
  const int  b_sl0  = t & 3;
  const char* Bg0 = (const char*)vT + (size_t)b_row0 * (NN * 2)
                  + (((b_sl0 ^ (b_row0 & 3)) << 4));
  const int  b_row1 = b_row0 + 256;      // i=1 rows 256..511
  const char* Bg1 = (const char*)vT + (size_t)b_row1 * (NN * 2)
                  + (((b_sl0 ^ (b_row1 & 3)) << 4));

  f32x4 acc[4][4];
#pragma unroll
  for (int i = 0; i < 4; ++i)
#pragma unroll
    for (int j = 0; j < 4; ++j) acc[i][j] = (f32x4){0.f, 0.f, 0.f, 0.f};

#define G1_ISSUE(tile, buf)                                                        \
  {                                                                                \
    GLOAD16(Agbase + (tile) * 128, lds + (buf) * 16384 + a_ldst);                  \
    char* bb = lds + 49152 + (buf) * 32768;                                        \
    GLOAD16(Bg0 + (tile) * 64, bb + t * 16);                                       \
    GLOAD16(Bg1 + (tile) * 64, bb + t * 16 + 16384);                               \
  }

#define G1_COMPUTE(aoff, boff)                                                     \
  {                                                                                \
    short8 af[4], bfr[4];                                                          \
    _Pragma("unroll")                                                              \
    for (int mi = 0; mi < 4; ++mi) {                                               \
      const int row = wr * 64 + mi * 16 + l15;                                     \
      const int X   = (row & 7) << 4;                                              \
      const char* rb = lds + (aoff) + row * 128;                                   \
      f32x4 lo = *(const f32x4*)(rb + ((q4 * 32) ^ X));                            \
      f32x4 hi = *(const f32x4*)(rb + ((q4 * 32 + 16) ^ X));                       \
      short8 a;                                                                    \
      _Pragma("unroll")                                                            \
      for (int j = 0; j < 4; ++j) { a[j] = f2bf(lo[j]); a[j + 4] = f2bf(hi[j]); }  \
      af[mi] = a;                                                                  \
    }                                                                              \
    _Pragma("unroll")                                                              \
    for (int ni = 0; ni < 4; ++ni) {                                               \
      const int row = wc * 64 + ni * 16 + l15;                                     \
      const int sl  = q4 ^ (row & 3);                                              \
      bfr[ni] = *(const short8*)(lds + (boff) + row * 64 + sl * 16);               \
    }                                                                              \
    _Pragma("unroll")                                                              \
    for (int mi = 0; mi < 4; ++mi)                                                 \
      _Pragma("unroll")                                                            \
      for (int ni = 0; ni < 4; ++ni)                                               \
        acc[mi][ni] = __builtin_amdgcn_mfma_f32_16x16x32_bf16(af[mi], bfr[ni],     \
                                                              acc[mi][ni], 0, 0, 0);\
  }

  // ---- prologue: tiles 0,1 in flight (6 loads) ----
  G1_ISSUE(0, 0);
  G1_ISSUE(1, 1);

  int cur = 0;                       // buf of tile kt
#pragma unroll 1
  for (int kt = 0; kt < 64; ++kt) {
    asm volatile("s_waitcnt vmcnt(3)" ::: "memory");   // tile kt landed; kt+1 in flight
    __builtin_amdgcn_sched_barrier(0);
    __builtin_amdgcn_s_barrier();                      // tile kt visible; buf(kt-1) free
    __builtin_amdgcn_sched_barrier(0);

    {
      const int tl = (kt + 2 < 64) ? kt + 2 : 63;      // clamped: uniform counts
      int ib = cur + 2; if (ib >= 3) ib -= 3;          // buf of tile kt+2 (= kt-1's)
      G1_ISSUE(tl, ib);
    }

    __builtin_amdgcn_s_setprio(1);
    G1_COMPUTE(cur * 16384, 49152 + cur * 32768);
    __builtin_amdgcn_s_setprio(0);

    ++cur; if (cur >= 3) cur = 0;
  }

  // ---- epilogue: C row = 4*q4+qq, col = l15 ----
#pragma unroll
  for (int mi = 0; mi < 4; ++mi) {
    const int nr = n0 + wr * 64 + mi * 16 + q4 * 4;
#pragma unroll
    for (int ni = 0; ni < 4; ++ni) {
      const int dc = p * DDIM + wc * 64 + ni * 16 + l15;
#pragma unroll
      for (int qq = 0; qq < 4; ++qq)
        SF[(size_t)(nr + qq) * PD + dc] = f2bf(acc[mi][ni][qq]);
    }
  }
#undef G1_ISSUE
#undef G1_COMPUTE
}

// ---------------------------------------------------------------------------
// G2: part[kc][n][h] = sum_{r in chunk kc} SF[n,r]*BmT[h,r]   (r6 proven)
// grid 544 = 17kc x 16n x 2h ; tile 128 x 256 x BK64 ; 48 KB LDS, 3 blk/CU
// ---------------------------------------------------------------------------
__global__ __launch_bounds__(512) void g_out_part(const short* __restrict__ SF,
                                                  const short* __restrict__ BmT,
                                                  float* __restrict__ part) {
  __shared__ __align__(16) char Asb[128 * 64 * 2];
  __shared__ __align__(16) char Bsb[256 * 64 * 2];
  const int t   = threadIdx.x;
  const int bid = blockIdx.x;
  const int kc  = bid >> 5;
  const int rem = bid & 31;
  const int n0  = (rem >> 1) * 128;
  const int h0  = (rem & 1) * 256;
  const int rbase = kc * 1536;
  const int lane = t & 63, w = t >> 6;
  const int wr = w >> 2, wc = w & 3;
  const int l15 = lane & 15, q4 = lane >> 4;

  f32x4 acc[4][4];
#pragma unroll
  for (int i = 0; i < 4; ++i)
#pragma unroll
    for (int j = 0; j < 4; ++j) acc[i][j] = (f32x4){0.f, 0.f, 0.f, 0.f};

  for (int kt = 0; kt < 24; ++kt) {
    const int rk = rbase + (kt << 6);
    __syncthreads();
#pragma unroll
    for (int i = 0; i < 2; ++i) {
      const int L   = t * 16 + i * 8192;
      const int row = L >> 7, cb = L & 127;
      const char* g = (const char*)SF + ((size_t)(n0 + row) * PD + rk) * 2
                    + (cb ^ ((row & 7) << 4));
      GLOAD16(g, Asb + L);
    }
#pragma unroll
    for (int i = 0; i < 4; ++i) {
      const int L   = t * 16 + i * 8192;
      const int row = L >> 7, cb = L & 127;
      const char* g = (const char*)BmT + ((size_t)(h0 + row) * PD + rk) * 2
                    + (cb ^ ((row & 7) << 4));
      GLOAD16(g, Bsb + L);
    }
    __syncthreads();
#pragma unroll
    for (int ks = 0; ks < 2; ++ks) {
      const int kb = ks * 64 + q4 * 16;
      short8 af[4], bfr[4];
#pragma unroll
      for (int mi = 0; mi < 4; ++mi) {
        const int row = wr * 64 + mi * 16 + l15;
        af[mi] = *(const short8*)(Asb + row * 128 + (kb ^ ((row & 7) << 4)));
      }
#pragma unroll
      for (int ni = 0; ni < 4; ++ni) {
        const int row = wc * 64 + ni * 16 + l15;
        bfr[ni] = *(const short8*)(Bsb + row * 128 + (kb ^ ((row & 7) << 4)));
      }
#pragma unroll
      for (int mi = 0; mi < 4; ++mi)
#pragma unroll
        for (int ni = 0; ni < 4; ++ni)
          acc[mi][ni] = __builtin_amdgcn_mfma_f32_16x16x32_bf16(af[mi], bfr[ni],
                                                                acc[mi][ni], 0, 0, 0);
    }
  }

  float* dst = part + (size_t)kc * (NN * HDIM);
#pragma unroll
  for (int mi = 0; mi < 4; ++mi) {
    const int nr = n0 + wr * 64 + mi * 16 + q4 * 4;
#pragma unroll
    for (int ni = 0; ni < 4; ++ni) {
      const int hc = h0 + wc * 64 + ni * 16 + l15;
#pragma unroll
      for (int qq = 0; qq < 4; ++qq)
        dst[(size_t)(nr + qq) * HDIM + hc] = acc[mi][ni][qq];
    }
  }
}

// ---------------------------------------------------------------------------
// K3: out[n,h] = B[h] + sum_kc part[kc][n][h]    (f32x4, fully coalesced)
// ---------------------------------------------------------------------------
__global__ __launch_bounds__(256) void k_reduce(const float* __restrict__ part,
                                                const float* __restrict__ B,
                                                float* __restrict__ out) {
  const int flat = (blockIdx.x * 256 + threadIdx.x) * 4;
  f32x4 s = *(const f32x4*)(B + (flat & (HDIM - 1)));
#pragma unroll
  for (int kc = 0; kc < NKC; ++kc)
    s += *(const f32x4*)(part + (size_t)kc * (NN * HDIM) + flat);
  *(f32x4*)(out + flat) = s;
}

// ---------------------------------------------------------------------------
// Workspace map (ws ~3.3 GB):
//   vT   [  0 MiB,   2 MiB)
//   BmT  [  2 MiB,  27.5MiB)
//   SF   [ 32 MiB, 134 MiB)
//   part [144 MiB, 212 MiB)
// ---------------------------------------------------------------------------
extern "C" void kernel_launch(void* const* d_in, const int* in_sizes, int n_in,
                              void* d_out, int out_size, void* d_ws, size_t ws_size,
                              hipStream_t stream) {
  const float* vertex = (const float*)d_in[0];
  const float* A      = (const float*)d_in[1];
  const float* W      = (const float*)d_in[2];
  const float* Wc     = (const float*)d_in[3];
  const float* B      = (const float*)d_in[4];
  float* out = (float*)d_out;

  char* ws   = (char*)d_ws;
  short* vT   = (short*)(ws);
  short* BmT  = (short*)(ws + (size_t)(2   << 20));
  short* SF   = (short*)(ws + (size_t)(32  << 20));
  float* part = (float*)(ws + (size_t)(144 << 20));

  k_transpose<<<dim3(256),  dim3(256),  0, stream>>>(vertex, vT);
  k_bmt      <<<dim3(512),  dim3(512),  0, stream>>>(W, Wc, BmT);
  g_supports <<<dim3(816),  dim3(1024), 0, stream>>>(A, vT, SF);
  g_out_part <<<dim3(544),  dim3(512),  0, stream>>>(SF, BmT, part);
  k_reduce   <<<dim3(1024), dim3(256),  0, stream>>>(part, B, out);
}

// Round 11
// 515.604 us; speedup vs baseline: 1.9854x; 1.0369x over previous
//
#include <hip/hip_runtime.h>
#include <hip/hip_bf16.h>

typedef __attribute__((ext_vector_type(8))) short short8;
typedef __attribute__((ext_vector_type(4))) float f32x4;

#define NN    2048
#define DDIM  512
#define HDIM  512
#define PP    51
#define NBASE 30
#define PD    26112   // PP*DDIM
#define NKC   17      // split-K factor in G2

static __device__ __forceinline__ short f2bf(float f) {
  __hip_bfloat16 h = __float2bfloat16(f);
  short s;
  __builtin_memcpy(&s, &h, 2);
  return s;
}

#define GLOAD16(gsrc, ldst)                                                              \
  __builtin_amdgcn_global_load_lds((const __attribute__((address_space(1))) void*)(gsrc),\
                                   (__attribute__((address_space(3))) void*)(ldst),      \
                                   16, 0, 0)

// ---------------------------------------------------------------------------
// K0: vertex [2048,512] f32 -> vT [512,2048] bf16
// ---------------------------------------------------------------------------
__global__ __launch_bounds__(256) void k_transpose(const float* __restrict__ vx,
                                                   short* __restrict__ vT) {
  __shared__ float tile[64][68];
  const int t  = threadIdx.x;
  const int mt = blockIdx.x & 31, dt = blockIdx.x >> 5;
  const int m0 = mt * 64, d0 = dt * 64;

  const int r  = t >> 2;
  const int c0 = (t & 3) * 16;
  const float* src = vx + (size_t)(m0 + r) * DDIM + d0 + c0;
#pragma unroll
  for (int j = 0; j < 4; ++j) {
    f32x4 v = *(const f32x4*)(src + j * 4);
    tile[r][c0 + j * 4 + 0] = v[0];
    tile[r][c0 + j * 4 + 1] = v[1];
    tile[r][c0 + j * 4 + 2] = v[2];
    tile[r][c0 + j * 4 + 3] = v[3];
  }
  __syncthreads();
  const int c  = t >> 2;
  const int r0 = (t & 3) * 16;
  short8 o0, o1;
#pragma unroll
  for (int j = 0; j < 8; ++j) {
    o0[j] = f2bf(tile[r0 + j][c]);
    o1[j] = f2bf(tile[r0 + 8 + j][c]);
  }
  short* dst = vT + (size_t)(d0 + c) * NN + m0 + r0;
  *(short8*)(dst)     = o0;
  *(short8*)(dst + 8) = o1;
}

// ---------------------------------------------------------------------------
// K1: BmT [512][26112] bf16 ; BmT[h][d'*51+p] = sum_b Wc[p,b]*W[(b*512+d')*512+h]
// ---------------------------------------------------------------------------
__global__ __launch_bounds__(512) void k_bmt(const float* __restrict__ W,
                                             const float* __restrict__ Wc,
                                             short* __restrict__ BmT) {
  __shared__ float wcs[PP * NBASE];
  __shared__ short Lt[HDIM * PP];
  const int t  = threadIdx.x;
  const int dp = blockIdx.x;

  for (int i = t; i < PP * NBASE; i += 512) wcs[i] = Wc[i];

  float wv[NBASE];
#pragma unroll
  for (int b = 0; b < NBASE; ++b)
    wv[b] = W[((size_t)(b * DDIM + dp)) * HDIM + t];
  __syncthreads();

#pragma unroll 1
  for (int p = 0; p < PP; ++p) {
    float acc = 0.f;
#pragma unroll
    for (int b = 0; b < NBASE; ++b) acc += wcs[p * NBASE + b] * wv[b];
    Lt[t * PP + p] = f2bf(acc);
  }
  __syncthreads();

  for (int idx = t; idx < HDIM * PP; idx += 512) {
    const int h = idx / PP;
    const int p = idx - h * PP;
    BmT[(size_t)h * PD + dp * PP + p] = Lt[idx];
  }
}

// ---------------------------------------------------------------------------
// G1: SF[n][p*512+d] = sum_m A[p,n,m]*vertex[m,d]
// 512 thr (8 waves 2x4, wave tile 64x64) ; tile 128(n) x 256(d) x BK32
// LDS 64 KB -> 2 blocks/CU (inter-block overlap hides barriers, m114).
// Both operands pure global_load_lds, dbuf, counted vmcnt(4), 2 barriers/iter:
//   A f32 128x128B rows, XOR (row&7)<<4, cvt f32->bf16 at frag read
//   B bf16 256x64B rows, slot-XOR q4^(row&3)            (r10-proven, 0 conflicts)
// grid 1632: d0-pair blocks 8 apart -> same XCD -> A panel L2/L3 reuse.
// ---------------------------------------------------------------------------
__global__ __launch_bounds__(512, 4) void g_supports(const float* __restrict__ A,
                                                     const short* __restrict__ vT,
                                                     short* __restrict__ SF) {
  __shared__ __align__(16) char lds[65536];   // A: 0,16K ; B: 32K,48K
  const int t    = threadIdx.x;
  const int bid  = blockIdx.x;
  const int p    = bid >> 5;
  const int rem  = bid & 31;
  const int d0   = ((rem >> 3) & 1) << 8;               // 0 / 256 (pairs 8 apart)
  const int n0   = (((rem & 7) | ((rem >> 4) << 3))) << 7;
  const int lane = t & 63, w = t >> 6;
  const int wr = w >> 2, wc = w & 3;
  const int l15 = lane & 15, q4 = lane >> 4;

  // A-issue: i=0/1 -> row = (t>>3)+i*64, 16B chunk (t&7), XOR-presrc
  const int a_row0 = t >> 3;
  const int a_cb   = (t & 7) << 4;
  const char* Ag0 = (const char*)A + ((size_t)p * NN * NN + (size_t)(n0 + a_row0) * NN) * 4
                  + (a_cb ^ ((a_row0 & 7) << 4));
  const int a_row1 = a_row0 + 64;
  const char* Ag1 = (const char*)A + ((size_t)p * NN * NN + (size_t)(n0 + a_row1) * NN) * 4
                  + (a_cb ^ ((a_row1 & 7) << 4));

  // B-issue: i=0/1 -> row = (t>>2)+i*128, slot (t&3), slot-XOR presrc
  const int b_row0 = t >> 2;
  const int b_sl   = t & 3;
  const char* Bg0 = (const char*)vT + (size_t)(d0 + b_row0) * (NN * 2)
                  + ((b_sl ^ (b_row0 & 3)) << 4);
  const int b_row1 = b_row0 + 128;
  const char* Bg1 = (const char*)vT + (size_t)(d0 + b_row1) * (NN * 2)
                  + ((b_sl ^ (b_row1 & 3)) << 4);

  f32x4 acc[4][4];
#pragma unroll
  for (int i = 0; i < 4; ++i)
#pragma unroll
    for (int j = 0; j < 4; ++j) acc[i][j] = (f32x4){0.f, 0.f, 0.f, 0.f};

#define G1_ISSUE(tile, buf)                                                        \
  {                                                                                \
    char* ab = lds + (buf) * 16384;                                                \
    GLOAD16(Ag0 + (size_t)(tile) * 128, ab + t * 16);                              \
    GLOAD16(Ag1 + (size_t)(tile) * 128, ab + t * 16 + 8192);                       \
    char* bb = lds + 32768 + (buf) * 16384;                                        \
    GLOAD16(Bg0 + (size_t)(tile) * 64, bb + t * 16);                               \
    GLOAD16(Bg1 + (size_t)(tile) * 64, bb + t * 16 + 8192);                        \
  }

#define G1_COMPUTE(buf)                                                            \
  {                                                                                \
    const char* ab = lds + (buf) * 16384;                                          \
    const char* bb = lds + 32768 + (buf) * 16384;                                  \
    short8 af[4], bfr[4];                                                          \
    _Pragma("unroll")                                                              \
    for (int mi = 0; mi < 4; ++mi) {                                               \
      const int row = wr * 64 + mi * 16 + l15;                                     \
      const int X   = (row & 7) << 4;                                              \
      const char* rb = ab + row * 128;                                             \
      f32x4 lo = *(const f32x4*)(rb + ((q4 * 32) ^ X));                            \
      f32x4 hi = *(const f32x4*)(rb + ((q4 * 32 + 16) ^ X));                       \
      short8 a;                                                                    \
      _Pragma("unroll")                                                            \
      for (int j = 0; j < 4; ++j) { a[j] = f2bf(lo[j]); a[j + 4] = f2bf(hi[j]); }  \
      af[mi] = a;                                                                  \
    }                                                                              \
    _Pragma("unroll")                                                              \
    for (int ni = 0; ni < 4; ++ni) {                                               \
      const int row = wc * 64 + ni * 16 + l15;                                     \
      const int sl  = q4 ^ (row & 3);                                              \
      bfr[ni] = *(const short8*)(bb + row * 64 + sl * 16);                         \
    }                                                                              \
    _Pragma("unroll")                                                              \
    for (int mi = 0; mi < 4; ++mi)                                                 \
      _Pragma("unroll")                                                            \
      for (int ni = 0; ni < 4; ++ni)                                               \
        acc[mi][ni] = __builtin_amdgcn_mfma_f32_16x16x32_bf16(af[mi], bfr[ni],     \
                                                              acc[mi][ni], 0, 0, 0);\
  }

  // ---- prologue: tiles 0,1 in flight (8 loads) ----
  G1_ISSUE(0, 0);
  G1_ISSUE(1, 1);

#pragma unroll 1
  for (int kt = 0; kt < 64; ++kt) {
    asm volatile("s_waitcnt vmcnt(4)" ::: "memory");   // tile kt landed; kt+1 in flight
    __builtin_amdgcn_sched_barrier(0);
    __builtin_amdgcn_s_barrier();                      // tile kt visible to all waves
    __builtin_amdgcn_sched_barrier(0);

    __builtin_amdgcn_s_setprio(1);
    G1_COMPUTE(kt & 1);
    __builtin_amdgcn_s_setprio(0);

    __builtin_amdgcn_s_barrier();                      // all waves done with buf kt&1
    __builtin_amdgcn_sched_barrier(0);
    {
      const int tl = (kt + 2 < 64) ? kt + 2 : 63;      // clamped: uniform counts
      G1_ISSUE(tl, kt & 1);                            // into buffer just freed
    }
  }

  // ---- epilogue: C row = 4*q4+qq, col = l15 ----
#pragma unroll
  for (int mi = 0; mi < 4; ++mi) {
    const int nr = n0 + wr * 64 + mi * 16 + q4 * 4;
#pragma unroll
    for (int ni = 0; ni < 4; ++ni) {
      const int dc = p * DDIM + d0 + wc * 64 + ni * 16 + l15;
#pragma unroll
      for (int qq = 0; qq < 4; ++qq)
        SF[(size_t)(nr + qq) * PD + dc] = f2bf(acc[mi][ni][qq]);
    }
  }
#undef G1_ISSUE
#undef G1_COMPUTE
}

// ---------------------------------------------------------------------------
// G2: part[kc][n][h] = sum_{r in chunk kc} SF[n,r]*BmT[h,r]   (r6 proven)
// grid 544 = 17kc x 16n x 2h ; tile 128 x 256 x BK64 ; 48 KB LDS, 3 blk/CU
// ---------------------------------------------------------------------------
__global__ __launch_bounds__(512) void g_out_part(const short* __restrict__ SF,
                                                  const short* __restrict__ BmT,
                                                  float* __restrict__ part) {
  __shared__ __align__(16) char Asb[128 * 64 * 2];
  __shared__ __align__(16) char Bsb[256 * 64 * 2];
  const int t   = threadIdx.x;
  const int bid = blockIdx.x;
  const int kc  = bid >> 5;
  const int rem = bid & 31;
  const int n0  = (rem >> 1) * 128;
  const int h0  = (rem & 1) * 256;
  const int rbase = kc * 1536;
  const int lane = t & 63, w = t >> 6;
  const int wr = w >> 2, wc = w & 3;
  const int l15 = lane & 15, q4 = lane >> 4;

  f32x4 acc[4][4];
#pragma unroll
  for (int i = 0; i < 4; ++i)
#pragma unroll
    for (int j = 0; j < 4; ++j) acc[i][j] = (f32x4){0.f, 0.f, 0.f, 0.f};

  for (int kt = 0; kt < 24; ++kt) {
    const int rk = rbase + (kt << 6);
    __syncthreads();
#pragma unroll
    for (int i = 0; i < 2; ++i) {
      const int L   = t * 16 + i * 8192;
      const int row = L >> 7, cb = L & 127;
      const char* g = (const char*)SF + ((size_t)(n0 + row) * PD + rk) * 2
                    + (cb ^ ((row & 7) << 4));
      GLOAD16(g, Asb + L);
    }
#pragma unroll
    for (int i = 0; i < 4; ++i) {
      const int L   = t * 16 + i * 8192;
      const int row = L >> 7, cb = L & 127;
      const char* g = (const char*)BmT + ((size_t)(h0 + row) * PD + rk) * 2
                    + (cb ^ ((row & 7) << 4));
      GLOAD16(g, Bsb + L);
    }
    __syncthreads();
#pragma unroll
    for (int ks = 0; ks < 2; ++ks) {
      const int kb = ks * 64 + q4 * 16;
      short8 af[4], bfr[4];
#pragma unroll
      for (int mi = 0; mi < 4; ++mi) {
        const int row = wr * 64 + mi * 16 + l15;
        af[mi] = *(const short8*)(Asb + row * 128 + (kb ^ ((row & 7) << 4)));
      }
#pragma unroll
      for (int ni = 0; ni < 4; ++ni) {
        const int row = wc * 64 + ni * 16 + l15;
        bfr[ni] = *(const short8*)(Bsb + row * 128 + (kb ^ ((row & 7) << 4)));
      }
#pragma unroll
      for (int mi = 0; mi < 4; ++mi)
#pragma unroll
        for (int ni = 0; ni < 4; ++ni)
          acc[mi][ni] = __builtin_amdgcn_mfma_f32_16x16x32_bf16(af[mi], bfr[ni],
                                                                acc[mi][ni], 0, 0, 0);
    }
  }

  float* dst = part + (size_t)kc * (NN * HDIM);
#pragma unroll
  for (int mi = 0; mi < 4; ++mi) {
    const int nr = n0 + wr * 64 + mi * 16 + q4 * 4;
#pragma unroll
    for (int ni = 0; ni < 4; ++ni) {
      const int hc = h0 + wc * 64 + ni * 16 + l15;
#pragma unroll
      for (int qq = 0; qq < 4; ++qq)
        dst[(size_t)(nr + qq) * HDIM + hc] = acc[mi][ni][qq];
    }
  }
}

// ---------------------------------------------------------------------------
// K3: out[n,h] = B[h] + sum_kc part[kc][n][h]    (f32x4, fully coalesced)
// ---------------------------------------------------------------------------
__global__ __launch_bounds__(256) void k_reduce(const float* __restrict__ part,
                                                const float* __restrict__ B,
                                                float* __restrict__ out) {
  const int flat = (blockIdx.x * 256 + threadIdx.x) * 4;
  f32x4 s = *(const f32x4*)(B + (flat & (HDIM - 1)));
#pragma unroll
  for (int kc = 0; kc < NKC; ++kc)
    s += *(const f32x4*)(part + (size_t)kc * (NN * HDIM) + flat);
  *(f32x4*)(out + flat) = s;
}

// ---------------------------------------------------------------------------
// Workspace map (ws ~3.3 GB):
//   vT   [  0 MiB,   2 MiB)
//   BmT  [  2 MiB,  27.5MiB)
//   SF   [ 32 MiB, 134 MiB)
//   part [144 MiB, 212 MiB)
// ---------------------------------------------------------------------------
extern "C" void kernel_launch(void* const* d_in, const int* in_sizes, int n_in,
                              void* d_out, int out_size, void* d_ws, size_t ws_size,
                              hipStream_t stream) {
  const float* vertex = (const float*)d_in[0];
  const float* A      = (const float*)d_in[1];
  const float* W      = (const float*)d_in[2];
  const float* Wc     = (const float*)d_in[3];
  const float* B      = (const float*)d_in[4];
  float* out = (float*)d_out;

  char* ws   = (char*)d_ws;
  short* vT   = (short*)(ws);
  short* BmT  = (short*)(ws + (size_t)(2   << 20));
  short* SF   = (short*)(ws + (size_t)(32  << 20));
  float* part = (float*)(ws + (size_t)(144 << 20));

  k_transpose<<<dim3(256),  dim3(256), 0, stream>>>(vertex, vT);
  k_bmt      <<<dim3(512),  dim3(512), 0, stream>>>(W, Wc, BmT);
  g_supports <<<dim3(1632), dim3(512), 0, stream>>>(A, vT, SF);
  g_out_part <<<dim3(544),  dim3(512), 0, stream>>>(SF, BmT, part);
  k_reduce   <<<dim3(1024), dim3(256), 0, stream>>>(part, B, out);
}